// Round 1
// baseline (258.059 us; speedup 1.0000x reference)
//
#include <hip/hip_runtime.h>
#include <hip/hip_bf16.h>
#include <stdint.h>

// Problem constants (match reference)
#define B_ 4096
#define C_ 200
#define P_ 32
#define F_ 512
#define N_ (C_*P_)        // 6400 prototypes total
#define ALPHA_ 5.0
#define EPS_ 1e-8

typedef unsigned short u16;
typedef __attribute__((ext_vector_type(8))) short short8;   // 8 bf16 (4 VGPRs) MFMA A/B frag
typedef __attribute__((ext_vector_type(4))) float floatx4;  // MFMA C/D frag

// ---------- bf16 convert (RNE) ----------
__device__ __forceinline__ u16 f2bf(float f) {
    union { float f; uint32_t u; } x; x.f = f;
    uint32_t r = x.u + 0x7fffu + ((x.u >> 16) & 1u);
    return (u16)(r >> 16);
}

__global__ void zero_kernel(double* sums) { sums[0] = 0.0; sums[1] = 0.0; }

__global__ void convert_kernel(const float* __restrict__ src, u16* __restrict__ dst) {
    int i = blockIdx.x * blockDim.x + threadIdx.x;
    float4 v = ((const float4*)src)[i];
    ushort4 o;
    o.x = f2bf(v.x); o.y = f2bf(v.y); o.z = f2bf(v.z); o.w = f2bf(v.w);
    ((ushort4*)dst)[i] = o;
}

// p2[n] = sum_f clusters[n][f]^2 in fp32 (one wave per prototype row)
__global__ void p2_kernel(const float* __restrict__ clusters, float* __restrict__ p2) {
    int row  = blockIdx.x * 4 + (threadIdx.x >> 6);
    int lane = threadIdx.x & 63;
    const float4* r = (const float4*)(clusters + (size_t)row * F_);
    float s = 0.f;
#pragma unroll
    for (int i = 0; i < 2; ++i) {
        float4 v = r[lane + i * 64];
        s += v.x*v.x + v.y*v.y + v.z*v.z + v.w*v.w;
    }
#pragma unroll
    for (int m = 32; m >= 1; m >>= 1) s += __shfl_xor(s, m);
    if (lane == 0) p2[row] = s;
}

// ---------- score kernel: bf16 MFMA GEMM + fused per-class min/argmin ----------
#define BM 128
#define BN 128
#define BK 32

typedef const __attribute__((address_space(1))) unsigned int gu32_t;
typedef __attribute__((address_space(3))) unsigned int lu32_t;

__device__ __forceinline__ void gld16(const u16* g, u16* l) {
    // async global->LDS, 16B per lane; LDS dest is wave-uniform base + lane*16
    __builtin_amdgcn_global_load_lds((gu32_t*)g, (lu32_t*)l, 16, 0, 0);
}

__global__ __launch_bounds__(256)
void score_kernel(const u16* __restrict__ Abf, const u16* __restrict__ Bbf,
                  const float* __restrict__ p2,
                  float* __restrict__ min_d, int* __restrict__ min_idx) {
    __shared__ __align__(16) u16 sA[BM * BK];   // 8 KB, row-major [row][k], 64B rows
    __shared__ __align__(16) u16 sB[BN * BK];   // 8 KB

    const int tid  = threadIdx.x;
    const int lane = tid & 63;
    const int w    = tid >> 6;          // wave 0..3
    const int wm   = w >> 1, wn = w & 1;
    const int bx   = blockIdx.x;        // n-tile 0..49
    const int by   = blockIdx.y;        // m-tile 0..31
    const int m0   = by * BM, n0 = bx * BN;
    const int mrow = lane & 15;         // M/N index within a 16x16 MFMA tile
    const int quad = lane >> 4;         // 0..3
    const int srow = lane >> 2;         // staging: row within 16-row group
    const int scol = (lane & 3) * 8;    // staging: bf16 col offset (8 elems = 16B)

    floatx4 zf = {0.f, 0.f, 0.f, 0.f};
    floatx4 acc[4][4];
#pragma unroll
    for (int i = 0; i < 4; ++i)
#pragma unroll
        for (int j = 0; j < 4; ++j) acc[i][j] = zf;

    for (int kt = 0; kt < F_ / BK; ++kt) {
        const int k0 = kt * BK;
        __syncthreads();  // previous iter's ds_reads done before overwrite
#pragma unroll
        for (int i = 0; i < 2; ++i) {
            int r0 = i * 64 + w * 16;   // wave-uniform 16-row group
            gld16(Abf + (size_t)(m0 + r0 + srow) * F_ + k0 + scol, sA + r0 * BK);
            gld16(Bbf + (size_t)(n0 + r0 + srow) * F_ + k0 + scol, sB + r0 * BK);
        }
        __syncthreads();  // drain global_load_lds (vmcnt) + barrier

        short8 af[4], bfr[4];
#pragma unroll
        for (int t = 0; t < 4; ++t) {
            af[t]  = *(const short8*)(sA + (wm * 64 + t * 16 + mrow) * BK + quad * 8);
            bfr[t] = *(const short8*)(sB + (wn * 64 + t * 16 + mrow) * BK + quad * 8);
        }
#pragma unroll
        for (int mt = 0; mt < 4; ++mt)
#pragma unroll
            for (int nt = 0; nt < 4; ++nt)
                acc[mt][nt] = __builtin_amdgcn_mfma_f32_16x16x32_bf16(af[mt], bfr[nt], acc[mt][nt], 0, 0, 0);
    }

    // Epilogue: score = p2[n] - 2*xp (x2 dropped: constant per row b, argmins unchanged).
    // C/D layout: col = lane&15, row = quad*4 + reg. Each wave: 64 rows x 2 classes.
    float pg[4];
#pragma unroll
    for (int nt = 0; nt < 4; ++nt) pg[nt] = p2[n0 + wn * 64 + nt * 16 + mrow];

#pragma unroll
    for (int ch = 0; ch < 2; ++ch) {
        const int cls = bx * 4 + wn * 2 + ch;
#pragma unroll
        for (int mt = 0; mt < 4; ++mt)
#pragma unroll
            for (int reg = 0; reg < 4; ++reg) {
                float v0 = pg[ch * 2]     - 2.0f * acc[mt][ch * 2][reg];     // p = mrow
                float v1 = pg[ch * 2 + 1] - 2.0f * acc[mt][ch * 2 + 1][reg]; // p = 16+mrow
                float v; int pi;
                if (v1 < v0) { v = v1; pi = 16 + mrow; } else { v = v0; pi = mrow; }
                // butterfly min+argmin over the 16 lanes sharing this row
#pragma unroll
                for (int m = 8; m >= 1; m >>= 1) {
                    float ov = __shfl_xor(v, m);
                    int   oi = __shfl_xor(pi, m);
                    if (ov < v || (ov == v && oi < pi)) { v = ov; pi = oi; }
                }
                if (mrow == 0) {
                    int grow = m0 + wm * 64 + mt * 16 + quad * 4 + reg;
                    min_d[grow * C_ + cls]   = v;
                    min_idx[grow * C_ + cls] = pi;
                }
            }
    }
}

// ---------- per-sample selection + exact fp32 distances ----------
__global__ void select_kernel(const float* __restrict__ X, const float* __restrict__ clusters,
                              const int* __restrict__ tgt, const float* __restrict__ min_d,
                              const int* __restrict__ min_idx, double* __restrict__ sums) {
    int b    = blockIdx.x * 4 + (threadIdx.x >> 6);
    int lane = threadIdx.x & 63;
    int tc   = tgt[b];

    float bv = 3.4e38f; int bc = 1 << 30;
    for (int c = lane; c < C_; c += 64) {
        float v = min_d[b * C_ + c];
        if (c != tc && (v < bv || (v == bv && c < bc))) { bv = v; bc = c; }
    }
#pragma unroll
    for (int m = 32; m >= 1; m >>= 1) {
        float ov = __shfl_xor(bv, m);
        int   oc = __shfl_xor(bc, m);
        if (ov < bv || (ov == bv && oc < bc)) { bv = ov; bc = oc; }
    }
    int ap = min_idx[b * C_ + tc];   // best proto in target class
    int wp = min_idx[b * C_ + bc];   // best proto in nearest wrong class

    const float4* xb = (const float4*)(X + (size_t)b * F_);
    const float4* pa = (const float4*)(clusters + ((size_t)tc * P_ + ap) * F_);
    const float4* pw = (const float4*)(clusters + ((size_t)bc * P_ + wp) * F_);
    float st = 0.f, sw = 0.f;
#pragma unroll
    for (int i = 0; i < 2; ++i) {
        float4 x = xb[lane + i * 64], a = pa[lane + i * 64], ww = pw[lane + i * 64];
        float dx = x.x - a.x, dy = x.y - a.y, dz = x.z - a.z, dw = x.w - a.w;
        st += dx*dx + dy*dy + dz*dz + dw*dw;
        dx = x.x - ww.x; dy = x.y - ww.y; dz = x.z - ww.z; dw = x.w - ww.w;
        sw += dx*dx + dy*dy + dz*dz + dw*dw;
    }
#pragma unroll
    for (int m = 32; m >= 1; m >>= 1) { st += __shfl_xor(st, m); sw += __shfl_xor(sw, m); }
    if (lane == 0) {
        atomicAdd(&sums[0], (double)st);
        atomicAdd(&sums[1], (double)sw);
    }
}

__global__ void finalize_kernel(const double* __restrict__ sums, float* __restrict__ out) {
    double denom = (double)B_ * (double)F_;
    double tl  = sums[0] / denom;
    double ntl = sums[1] / denom;
    out[0] = (float)((1.0 - ALPHA_) * tl + ALPHA_ / (ntl + EPS_));
}

// ---------- launch ----------
extern "C" void kernel_launch(void* const* d_in, const int* in_sizes, int n_in,
                              void* d_out, int out_size, void* d_ws, size_t ws_size,
                              hipStream_t stream) {
    const float* outputs  = (const float*)d_in[0];
    const float* clusters = (const float*)d_in[1];
    const int*   tgt      = (const int*)d_in[2];
    float* out = (float*)d_out;

    char* ws = (char*)d_ws;
    // workspace layout (all offsets 16B-aligned), total 17,327,120 bytes
    u16*    Abf     = (u16*)(ws);                    // 4096*512*2  = 4,194,304
    u16*    Bbf     = (u16*)(ws + 4194304);          // 6400*512*2  = 6,553,600
    float*  p2      = (float*)(ws + 10747904);       // 6400*4      =    25,600
    float*  min_d   = (float*)(ws + 10773504);       // 4096*200*4  = 3,276,800
    int*    min_idx = (int*)(ws + 14050304);         // 4096*200*4  = 3,276,800
    double* sums    = (double*)(ws + 17327104);      // 2*8

    zero_kernel<<<1, 1, 0, stream>>>(sums);
    convert_kernel<<<(B_ * F_ / 4) / 256, 256, 0, stream>>>(outputs, Abf);    // 2048 blocks
    convert_kernel<<<(N_ * F_ / 4) / 256, 256, 0, stream>>>(clusters, Bbf);   // 3200 blocks
    p2_kernel<<<N_ / 4, 256, 0, stream>>>(clusters, p2);                      // 1600 blocks
    score_kernel<<<dim3(N_ / BN, B_ / BM), 256, 0, stream>>>(Abf, Bbf, p2, min_d, min_idx);
    select_kernel<<<B_ / 4, 256, 0, stream>>>(outputs, clusters, tgt, min_d, min_idx, sums);
    finalize_kernel<<<1, 1, 0, stream>>>(sums, out);
}

// Round 2
// 160.546 us; speedup vs baseline: 1.6074x; 1.6074x over previous
//
#include <hip/hip_runtime.h>
#include <hip/hip_bf16.h>
#include <stdint.h>

// Problem constants (match reference)
#define B_ 4096
#define C_ 200
#define P_ 32
#define F_ 512
#define N_ (C_*P_)        // 6400 prototypes total
#define ALPHA_ 5.0
#define EPS_ 1e-8

typedef unsigned short u16;
typedef __attribute__((ext_vector_type(8))) short short8;   // 8 bf16 (4 VGPRs) MFMA A/B frag
typedef __attribute__((ext_vector_type(4))) float floatx4;  // MFMA C/D frag

// ---------- bf16 convert (RNE) ----------
__device__ __forceinline__ u16 f2bf(float f) {
    union { float f; uint32_t u; } x; x.f = f;
    uint32_t r = x.u + 0x7fffu + ((x.u >> 16) & 1u);
    return (u16)(r >> 16);
}

__global__ void convert_kernel(const float* __restrict__ src, u16* __restrict__ dst) {
    int i = blockIdx.x * blockDim.x + threadIdx.x;
    float4 v = ((const float4*)src)[i];
    ushort4 o;
    o.x = f2bf(v.x); o.y = f2bf(v.y); o.z = f2bf(v.z); o.w = f2bf(v.w);
    ((ushort4*)dst)[i] = o;
}

// p2[n] = sum_f clusters[n][f]^2 in fp32 (one wave per prototype row)
__global__ void p2_kernel(const float* __restrict__ clusters, float* __restrict__ p2) {
    int row  = blockIdx.x * 4 + (threadIdx.x >> 6);
    int lane = threadIdx.x & 63;
    const float4* r = (const float4*)(clusters + (size_t)row * F_);
    float s = 0.f;
#pragma unroll
    for (int i = 0; i < 2; ++i) {
        float4 v = r[lane + i * 64];
        s += v.x*v.x + v.y*v.y + v.z*v.z + v.w*v.w;
    }
#pragma unroll
    for (int m = 32; m >= 1; m >>= 1) s += __shfl_xor(s, m);
    if (lane == 0) p2[row] = s;
}

// ---------- score kernel: bf16 MFMA GEMM + fused per-class min/argmin ----------
#define BM 128
#define BN 128
#define BK 32

typedef const __attribute__((address_space(1))) unsigned int gu32_t;
typedef __attribute__((address_space(3))) unsigned int lu32_t;

__device__ __forceinline__ void gld16(const u16* g, u16* l) {
    // async global->LDS, 16B per lane; LDS dest is wave-uniform base + lane*16
    __builtin_amdgcn_global_load_lds((gu32_t*)g, (lu32_t*)l, 16, 0, 0);
}

__global__ __launch_bounds__(256)
void score_kernel(const u16* __restrict__ Abf, const u16* __restrict__ Bbf,
                  const float* __restrict__ p2,
                  float* __restrict__ min_d, int* __restrict__ min_idx) {
    __shared__ __align__(16) u16 sA[BM * BK];   // 8 KB, row-major [row][k], 64B rows
    __shared__ __align__(16) u16 sB[BN * BK];   // 8 KB

    const int tid  = threadIdx.x;
    const int lane = tid & 63;
    const int w    = tid >> 6;          // wave 0..3
    const int wm   = w >> 1, wn = w & 1;
    const int bx   = blockIdx.x;        // n-tile 0..49
    const int by   = blockIdx.y;        // m-tile 0..31
    const int m0   = by * BM, n0 = bx * BN;
    const int mrow = lane & 15;         // M/N index within a 16x16 MFMA tile
    const int quad = lane >> 4;         // 0..3
    const int srow = lane >> 2;         // staging: row within 16-row group
    const int scol = (lane & 3) * 8;    // staging: bf16 col offset (8 elems = 16B)

    floatx4 zf = {0.f, 0.f, 0.f, 0.f};
    floatx4 acc[4][4];
#pragma unroll
    for (int i = 0; i < 4; ++i)
#pragma unroll
        for (int j = 0; j < 4; ++j) acc[i][j] = zf;

    for (int kt = 0; kt < F_ / BK; ++kt) {
        const int k0 = kt * BK;
        __syncthreads();  // previous iter's ds_reads done before overwrite
#pragma unroll
        for (int i = 0; i < 2; ++i) {
            int r0 = i * 64 + w * 16;   // wave-uniform 16-row group
            gld16(Abf + (size_t)(m0 + r0 + srow) * F_ + k0 + scol, sA + r0 * BK);
            gld16(Bbf + (size_t)(n0 + r0 + srow) * F_ + k0 + scol, sB + r0 * BK);
        }
        __syncthreads();  // drain global_load_lds (vmcnt) + barrier

        short8 af[4], bfr[4];
#pragma unroll
        for (int t = 0; t < 4; ++t) {
            af[t]  = *(const short8*)(sA + (wm * 64 + t * 16 + mrow) * BK + quad * 8);
            bfr[t] = *(const short8*)(sB + (wn * 64 + t * 16 + mrow) * BK + quad * 8);
        }
#pragma unroll
        for (int mt = 0; mt < 4; ++mt)
#pragma unroll
            for (int nt = 0; nt < 4; ++nt)
                acc[mt][nt] = __builtin_amdgcn_mfma_f32_16x16x32_bf16(af[mt], bfr[nt], acc[mt][nt], 0, 0, 0);
    }

    // Epilogue: score = p2[n] - 2*xp (x2 dropped: constant per row b, argmins unchanged).
    // C/D layout: col = lane&15, row = quad*4 + reg. Each wave: 64 rows x 2 classes.
    float pg[4];
#pragma unroll
    for (int nt = 0; nt < 4; ++nt) pg[nt] = p2[n0 + wn * 64 + nt * 16 + mrow];

#pragma unroll
    for (int ch = 0; ch < 2; ++ch) {
        const int cls = bx * 4 + wn * 2 + ch;
#pragma unroll
        for (int mt = 0; mt < 4; ++mt)
#pragma unroll
            for (int reg = 0; reg < 4; ++reg) {
                float v0 = pg[ch * 2]     - 2.0f * acc[mt][ch * 2][reg];     // p = mrow
                float v1 = pg[ch * 2 + 1] - 2.0f * acc[mt][ch * 2 + 1][reg]; // p = 16+mrow
                float v; int pi;
                if (v1 < v0) { v = v1; pi = 16 + mrow; } else { v = v0; pi = mrow; }
                // butterfly min+argmin over the 16 lanes sharing this row
#pragma unroll
                for (int m = 8; m >= 1; m >>= 1) {
                    float ov = __shfl_xor(v, m);
                    int   oi = __shfl_xor(pi, m);
                    if (ov < v || (ov == v && oi < pi)) { v = ov; pi = oi; }
                }
                if (mrow == 0) {
                    int grow = m0 + wm * 64 + mt * 16 + quad * 4 + reg;
                    min_d[grow * C_ + cls]   = v;
                    min_idx[grow * C_ + cls] = pi;
                }
            }
    }
}

// ---------- per-sample selection + exact fp32 distances (no atomics) ----------
__global__ void select_kernel(const float* __restrict__ X, const float* __restrict__ clusters,
                              const int* __restrict__ tgt, const float* __restrict__ min_d,
                              const int* __restrict__ min_idx,
                              float* __restrict__ stw, float* __restrict__ sww) {
    int b    = blockIdx.x * 4 + (threadIdx.x >> 6);
    int lane = threadIdx.x & 63;
    int tc   = tgt[b];

    float bv = 3.4e38f; int bc = 1 << 30;
    for (int c = lane; c < C_; c += 64) {
        float v = min_d[b * C_ + c];
        if (c != tc && (v < bv || (v == bv && c < bc))) { bv = v; bc = c; }
    }
#pragma unroll
    for (int m = 32; m >= 1; m >>= 1) {
        float ov = __shfl_xor(bv, m);
        int   oc = __shfl_xor(bc, m);
        if (ov < bv || (ov == bv && oc < bc)) { bv = ov; bc = oc; }
    }
    int ap = min_idx[b * C_ + tc];   // best proto in target class
    int wp = min_idx[b * C_ + bc];   // best proto in nearest wrong class

    const float4* xb = (const float4*)(X + (size_t)b * F_);
    const float4* pa = (const float4*)(clusters + ((size_t)tc * P_ + ap) * F_);
    const float4* pw = (const float4*)(clusters + ((size_t)bc * P_ + wp) * F_);
    float st = 0.f, sw = 0.f;
#pragma unroll
    for (int i = 0; i < 2; ++i) {
        float4 x = xb[lane + i * 64], a = pa[lane + i * 64], ww = pw[lane + i * 64];
        float dx = x.x - a.x, dy = x.y - a.y, dz = x.z - a.z, dw = x.w - a.w;
        st += dx*dx + dy*dy + dz*dz + dw*dw;
        dx = x.x - ww.x; dy = x.y - ww.y; dz = x.z - ww.z; dw = x.w - ww.w;
        sw += dx*dx + dy*dy + dz*dz + dw*dw;
    }
#pragma unroll
    for (int m = 32; m >= 1; m >>= 1) { st += __shfl_xor(st, m); sw += __shfl_xor(sw, m); }
    if (lane == 0) { stw[b] = st; sww[b] = sw; }
}

// Single-block reduction of 2x4096 floats + final loss
__global__ __launch_bounds__(1024)
void finalize_kernel(const float* __restrict__ stw, const float* __restrict__ sww,
                     float* __restrict__ out) {
    __shared__ float r1[16], r2[16];
    int tid = threadIdx.x;
    float s1 = 0.f, s2 = 0.f;
#pragma unroll
    for (int i = 0; i < 4; ++i) {
        s1 += stw[tid + i * 1024];
        s2 += sww[tid + i * 1024];
    }
#pragma unroll
    for (int m = 32; m >= 1; m >>= 1) { s1 += __shfl_xor(s1, m); s2 += __shfl_xor(s2, m); }
    if ((tid & 63) == 0) { r1[tid >> 6] = s1; r2[tid >> 6] = s2; }
    __syncthreads();
    if (tid == 0) {
        double t1 = 0.0, t2 = 0.0;
#pragma unroll
        for (int i = 0; i < 16; ++i) { t1 += (double)r1[i]; t2 += (double)r2[i]; }
        double denom = (double)B_ * (double)F_;
        double tl  = t1 / denom;
        double ntl = t2 / denom;
        out[0] = (float)((1.0 - ALPHA_) * tl + ALPHA_ / (ntl + EPS_));
    }
}

// ---------- launch ----------
extern "C" void kernel_launch(void* const* d_in, const int* in_sizes, int n_in,
                              void* d_out, int out_size, void* d_ws, size_t ws_size,
                              hipStream_t stream) {
    const float* outputs  = (const float*)d_in[0];
    const float* clusters = (const float*)d_in[1];
    const int*   tgt      = (const int*)d_in[2];
    float* out = (float*)d_out;

    char* ws = (char*)d_ws;
    // workspace layout (16B-aligned), total 17,327,104 bytes (known to fit)
    u16*    Abf     = (u16*)(ws);                    // 4096*512*2  = 4,194,304
    u16*    Bbf     = (u16*)(ws + 4194304);          // 6400*512*2  = 6,553,600
    float*  p2      = (float*)(ws + 10747904);       // 6400*4      =    25,600
    float*  min_d   = (float*)(ws + 10773504);       // 4096*200*4  = 3,276,800
    int*    min_idx = (int*)(ws + 14050304);         // 4096*200*4  = 3,276,800
    // per-sample partials: reuse the Abf region (dead after score_kernel)
    float*  stw     = (float*)(ws);                  // 4096*4 = 16 KB
    float*  sww     = (float*)(ws + 16384);          // 4096*4 = 16 KB

    convert_kernel<<<(B_ * F_ / 4) / 256, 256, 0, stream>>>(outputs, Abf);    // 2048 blocks
    convert_kernel<<<(N_ * F_ / 4) / 256, 256, 0, stream>>>(clusters, Bbf);   // 3200 blocks
    p2_kernel<<<N_ / 4, 256, 0, stream>>>(clusters, p2);                      // 1600 blocks
    score_kernel<<<dim3(N_ / BN, B_ / BM), 256, 0, stream>>>(Abf, Bbf, p2, min_d, min_idx);
    select_kernel<<<B_ / 4, 256, 0, stream>>>(outputs, clusters, tgt, min_d, min_idx, stw, sww);
    finalize_kernel<<<1, 1024, 0, stream>>>(stw, sww, out);
}